// Round 7
// baseline (140.215 us; speedup 1.0000x reference)
//
#include <hip/hip_runtime.h>

#define S_LEN 2048
#define D_MODEL 1024
#define NB 4

typedef unsigned short u16;
typedef __attribute__((ext_vector_type(8))) short short8;
typedef __attribute__((ext_vector_type(4))) float f32x4;
typedef __attribute__((ext_vector_type(4))) unsigned short u16x4;

__device__ inline u16 f2bf(float f) {
  union { float f; unsigned u; } v; v.f = f;
  unsigned u = v.u;
  unsigned r = (u + 0x7FFFu + ((u >> 16) & 1u)) >> 16;
  return (u16)r;
}

__device__ inline float bf2f(u16 b) {
  union { unsigned u; float f; } v; v.u = ((unsigned)b) << 16;
  return v.f;
}

__device__ inline void glds16(const void* g, void* l) {
  __builtin_amdgcn_global_load_lds((const __attribute__((address_space(1))) void*)g,
                                   (__attribute__((address_space(3))) void*)l,
                                   16, 0, 0);
}

// ---------------- LayerNorm (fp32 in -> bf16 out) + fused bvec[r] = dot(xn, w2)/D ----------------
__global__ __launch_bounds__(256) void ln_kernel(const float* __restrict__ ctx,
                                                 const float* __restrict__ gamma,
                                                 const float* __restrict__ beta,
                                                 const float* __restrict__ w2,
                                                 u16* __restrict__ xb,
                                                 float* __restrict__ bvec) {
  const int row = blockIdx.x;
  const int t = threadIdx.x;
  const f32x4 v = ((const f32x4*)(ctx + (size_t)row * D_MODEL))[t];
  float s = v[0] + v[1] + v[2] + v[3];
  float q = v[0]*v[0] + v[1]*v[1] + v[2]*v[2] + v[3]*v[3];
  for (int o = 32; o > 0; o >>= 1) { s += __shfl_xor(s, o); q += __shfl_xor(q, o); }
  __shared__ float rs[4], rq[4], rd[4];
  const int wave = t >> 6, lane = t & 63;
  if (lane == 0) { rs[wave] = s; rq[wave] = q; }
  __syncthreads();
  s = rs[0] + rs[1] + rs[2] + rs[3];
  q = rq[0] + rq[1] + rq[2] + rq[3];
  const float mu = s * (1.0f / D_MODEL);
  const float var = q * (1.0f / D_MODEL) - mu * mu;
  const float rstd = rsqrtf(var + 1e-3f);
  const f32x4 g4 = ((const f32x4*)gamma)[t];
  const f32x4 b4 = ((const f32x4*)beta)[t];
  const f32x4 w4 = ((const f32x4*)w2)[t];
  float xv[4];
  float dot = 0.0f;
  #pragma unroll
  for (int u = 0; u < 4; ++u) {
    xv[u] = (v[u] - mu) * rstd * g4[u] + b4[u];
    dot += xv[u] * w4[u];
  }
  u16x4 o;
  #pragma unroll
  for (int u = 0; u < 4; ++u) o[u] = f2bf(xv[u]);
  ((u16x4*)(xb + (size_t)row * D_MODEL))[t] = o;
  for (int of = 32; of > 0; of >>= 1) dot += __shfl_xor(dot, of);
  if (lane == 0) rd[wave] = dot;
  __syncthreads();
  if (t == 0) bvec[row] = (rd[0] + rd[1] + rd[2] + rd[3]) * (1.0f / D_MODEL);
}

// ---------------- weight prep (+ fused w2 = Wk·bq at blockIdx.y==64) ----------------
// Wt[n][k] = bf16(W[k][n]); rows [0,1024)=Wq^T, [1024,2048)=Wk^T
__global__ __launch_bounds__(256) void prep_w(const float* __restrict__ Wq,
                                              const float* __restrict__ Wk,
                                              const float* __restrict__ bq,
                                              u16* __restrict__ Wt,
                                              float* __restrict__ w2) {
  if (blockIdx.y == 64) {
    // w2[r] = sum_n Wk[r][n] * bq[n]; 32 blocks x 4 waves x 8 rows
    const int tid = threadIdx.y * 32 + threadIdx.x;
    const int wave = tid >> 6, lane = tid & 63;
    const int r0 = blockIdx.x * 32 + wave * 8;
    #pragma unroll
    for (int rr = 0; rr < 8; ++rr) {
      const int r = r0 + rr;
      const f32x4* row = (const f32x4*)(Wk + (size_t)r * D_MODEL);
      float s = 0.0f;
      #pragma unroll
      for (int c = 0; c < 4; ++c) {
        const f32x4 v = row[lane * 4 + c];
        const f32x4 b = ((const f32x4*)bq)[lane * 4 + c];
        s += v[0]*b[0] + v[1]*b[1] + v[2]*b[2] + v[3]*b[3];
      }
      for (int o = 32; o > 0; o >>= 1) s += __shfl_xor(s, o);
      if (lane == 0) w2[r] = s;
    }
    return;
  }
  __shared__ float tile[32][33];
  const int k0 = blockIdx.x * 32;
  const int n0 = blockIdx.y * 32;
  const int tx = threadIdx.x, ty = threadIdx.y;
  const float* W = (n0 < D_MODEL) ? Wq : Wk;
  const int nl0 = (n0 < D_MODEL) ? n0 : (n0 - D_MODEL);
  #pragma unroll
  for (int j = 0; j < 32; j += 8)
    tile[ty + j][tx] = W[(size_t)(k0 + ty + j) * D_MODEL + nl0 + tx];
  __syncthreads();
  #pragma unroll
  for (int j = 0; j < 32; j += 8)
    Wt[(size_t)(n0 + ty + j) * D_MODEL + k0 + tx] = f2bf(tile[tx][ty + j]);
}

// ---------------- bf16 GEMM: m97-style 128x128 tile (kept for PT) ----------------
__global__ __launch_bounds__(256, 2) void gemm_bt(
    const u16* __restrict__ A, int lda, long long sA,
    const u16* __restrict__ Bt, int ldb, long long sB,
    u16* __restrict__ C, int ldc, long long sC,
    float scale, int K) {
  __shared__ u16 As[128][32];
  __shared__ u16 Bs[128][32];
  const int tid = threadIdx.x;
  const int wave = tid >> 6, lane = tid & 63;
  const int z = blockIdx.z;
  A += (size_t)z * sA;
  Bt += (size_t)z * sB;
  const size_t m0 = (size_t)blockIdx.y * 128;
  const size_t n0 = (size_t)blockIdx.x * 128;
  const int wr = (wave >> 1) * 64;
  const int wc = (wave & 1) * 64;
  const int strow = wave * 16 + (lane >> 2);
  const int stslot = (lane & 3) * 8;
  const int fr = lane & 15, fq = lane >> 4;

  f32x4 acc[4][4];
  #pragma unroll
  for (int i = 0; i < 4; ++i)
    #pragma unroll
    for (int j = 0; j < 4; ++j) acc[i][j] = (f32x4)(0.0f);

  for (int k0 = 0; k0 < K; k0 += 32) {
    const u16* ga = A + (m0 + strow) * lda + k0 + stslot;
    const u16* gb = Bt + (n0 + strow) * ldb + k0 + stslot;
    glds16(ga, &As[wave * 16][0]);
    glds16(ga + (size_t)64 * lda, &As[64 + wave * 16][0]);
    glds16(gb, &Bs[wave * 16][0]);
    glds16(gb + (size_t)64 * ldb, &Bs[64 + wave * 16][0]);
    __syncthreads();
    short8 af[4], bfv[4];
    #pragma unroll
    for (int mi = 0; mi < 4; ++mi) af[mi] = *(const short8*)&As[wr + mi * 16 + fr][fq * 8];
    #pragma unroll
    for (int ni = 0; ni < 4; ++ni) bfv[ni] = *(const short8*)&Bs[wc + ni * 16 + fr][fq * 8];
    #pragma unroll
    for (int mi = 0; mi < 4; ++mi)
      #pragma unroll
      for (int ni = 0; ni < 4; ++ni)
        acc[mi][ni] = __builtin_amdgcn_mfma_f32_16x16x32_bf16(af[mi], bfv[ni], acc[mi][ni], 0, 0, 0);
    __syncthreads();
  }

  #pragma unroll
  for (int mi = 0; mi < 4; ++mi)
    #pragma unroll
    for (int ni = 0; ni < 4; ++ni) {
      const size_t row = m0 + wr + mi * 16 + fq * 4;
      const size_t col = n0 + wc + ni * 16 + fr;
      #pragma unroll
      for (int r = 0; r < 4; ++r)
        C[((size_t)z * sC) + (row + r) * ldc + col] = f2bf(acc[mi][ni][r] * scale);
    }
}

// ---------------- 256x256 8-phase bf16 GEMM (scores), BK=64, 8 waves, 1D grid ----------------
// XCD partition (blocks all co-resident, 1/CU): xcd = p&7 owns (batch z=xcd>>1, row-half xcd&1):
// 4 A-panels (2MB) + 8 B-panels (4MB) = 6MB/XCD L2 working set.
__global__ __launch_bounds__(512, 2) void gemm8p256(
    const u16* __restrict__ A, int lda, long long sA,
    const u16* __restrict__ Bt, int ldb, long long sB,
    u16* __restrict__ C, int ldc, long long sC,
    float scale, int K) {
  __shared__ char smem[131072];
  const int tid = threadIdx.x;
  const int wave = tid >> 6, lane = tid & 63;
  const int fr = lane & 15, fq = lane >> 4;
  const int wm = wave >> 2, wn = wave & 3;
  const int p = blockIdx.x;
  const int xcd = p & 7, sidx = p >> 3;
  const int z = xcd >> 1;
  const size_t m0 = (size_t)((xcd & 1) * 4 + (sidx >> 3)) * 256;
  const size_t n0 = (size_t)(sidx & 7) * 256;
  const u16* Ab = A + (size_t)z * sA + m0 * lda;
  const u16* Bb = Bt + (size_t)z * sB + n0 * ldb;
  const int perA = (lane >> 3) * lda + (((lane & 7) ^ (lane >> 3)) * 8);
  const int perB = (lane >> 3) * ldb + (((lane & 7) ^ (lane >> 3)) * 8);
  const int u0v = wave * 2, u1v = wave * 2 + 1;
  const int rA_0 = (u0v & 7) * 8 + (u0v >> 3) * 128;
  const int rA_1 = (u1v & 7) * 8 + (u1v >> 3) * 128;
  const int rB_0 = (u0v >> 2) * 64 + (u0v & 3) * 8;
  const int rB_1 = (u1v >> 2) * 64 + (u1v & 3) * 8;
  const int sw0 = ((fq) ^ (fr & 7)) * 16;
  const int sw1 = ((4 + fq) ^ (fr & 7)) * 16;
  const int aBase = wm * 16384 + fr * 128;
  const int bBase = 32768 + wn * 8192 + fr * 128;

  f32x4 acc[8][4];
  #pragma unroll
  for (int i = 0; i < 8; ++i)
    #pragma unroll
    for (int j = 0; j < 4; ++j) acc[i][j] = (f32x4)(0.0f);

#define STG_A02(BUF, KK) do { \
    glds16(Ab + (size_t)rA_0 * lda + perA + (KK), smem + (BUF) + rA_0 * 128); \
    glds16(Ab + (size_t)rA_1 * lda + perA + (KK), smem + (BUF) + rA_1 * 128); } while (0)
#define STG_A13(BUF, KK) do { \
    glds16(Ab + (size_t)(rA_0 + 64) * lda + perA + (KK), smem + (BUF) + (rA_0 + 64) * 128); \
    glds16(Ab + (size_t)(rA_1 + 64) * lda + perA + (KK), smem + (BUF) + (rA_1 + 64) * 128); } while (0)
#define STG_BEV(BUF, KK) do { \
    glds16(Bb + (size_t)rB_0 * ldb + perB + (KK), smem + (BUF) + 32768 + rB_0 * 128); \
    glds16(Bb + (size_t)rB_1 * ldb + perB + (KK), smem + (BUF) + 32768 + rB_1 * 128); } while (0)
#define STG_BOD(BUF, KK) do { \
    glds16(Bb + (size_t)(rB_0 + 32) * ldb + perB + (KK), smem + (BUF) + 32768 + (rB_0 + 32) * 128); \
    glds16(Bb + (size_t)(rB_1 + 32) * ldb + perB + (KK), smem + (BUF) + 32768 + (rB_1 + 32) * 128); } while (0)

  const int NT = K >> 6;
  STG_A02(0, 0); STG_BEV(0, 0); STG_BOD(0, 0); STG_A13(0, 0);
  STG_A02(65536, (NT > 1) ? 64 : 0);

  for (int t = 0; t < NT; ++t) {
    const int bo = (t & 1) * 65536;
    const int bn = bo ^ 65536;
    const int kk  = (t + 1 < NT) ? (t + 1) * 64 : 0;
    const int kk2 = (t + 2 < NT) ? (t + 2) * 64 : 0;
    short8 a0[8], a1[8], be[4], bod[4];

    // ---- phase 0 ----
    asm volatile("s_waitcnt vmcnt(6)" ::: "memory");
    asm volatile("s_barrier" ::: "memory");
    #pragma unroll
    for (int fi = 0; fi < 4; ++fi) {
      a0[fi * 2 + 0] = *(const short8*)(smem + bo + aBase + fi * 2048 + sw0);
      a0[fi * 2 + 1] = *(const short8*)(smem + bo + aBase + fi * 2048 + sw1);
    }
    #pragma unroll
    for (int nj = 0; nj < 2; ++nj) {
      be[nj * 2 + 0] = *(const short8*)(smem + bo + bBase + nj * 2048 + sw0);
      be[nj * 2 + 1] = *(const short8*)(smem + bo + bBase + nj * 2048 + sw1);
    }
    STG_BEV(bn, kk);
    __builtin_amdgcn_s_setprio(1);
    #pragma unroll
    for (int ks = 0; ks < 2; ++ks)
      #pragma unroll
      for (int fi = 0; fi < 4; ++fi)
        #pragma unroll
        for (int nj = 0; nj < 2; ++nj)
          acc[fi][nj] = __builtin_amdgcn_mfma_f32_16x16x32_bf16(a0[fi * 2 + ks], be[nj * 2 + ks], acc[fi][nj], 0, 0, 0);
    __builtin_amdgcn_s_setprio(0);

    // ---- phase 1 ----
    asm volatile("s_waitcnt vmcnt(6)" ::: "memory");
    asm volatile("s_barrier" ::: "memory");
    #pragma unroll
    for (int nj = 0; nj < 2; ++nj) {
      bod[nj * 2 + 0] = *(const short8*)(smem + bo + bBase + 4096 + nj * 2048 + sw0);
      bod[nj * 2 + 1] = *(const short8*)(smem + bo + bBase + 4096 + nj * 2048 + sw1);
    }
    STG_BOD(bn, kk);
    __builtin_amdgcn_s_setprio(1);
    #pragma unroll
    for (int ks = 0; ks < 2; ++ks)
      #pragma unroll
      for (int fi = 0; fi < 4; ++fi)
        #pragma unroll
        for (int nj = 0; nj < 2; ++nj)
          acc[fi][2 + nj] = __builtin_amdgcn_mfma_f32_16x16x32_bf16(a0[fi * 2 + ks], bod[nj * 2 + ks], acc[fi][2 + nj], 0, 0, 0);
    __builtin_amdgcn_s_setprio(0);

    // ---- phase 2 ----
    asm volatile("s_waitcnt vmcnt(6)" ::: "memory");
    asm volatile("s_barrier" ::: "memory");
    #pragma unroll
    for (int fi = 0; fi < 4; ++fi) {
      a1[fi * 2 + 0] = *(const short8*)(smem + bo + aBase + 8192 + fi * 2048 + sw0);
      a1[fi * 2 + 1] = *(const short8*)(smem + bo + aBase + 8192 + fi * 2048 + sw1);
    }
    STG_A13(bn, kk);
    __builtin_amdgcn_s_setprio(1);
    #pragma unroll
    for (int ks = 0; ks < 2; ++ks)
      #pragma unroll
      for (int fi = 0; fi < 4; ++fi)
        #pragma unroll
        for (int nj = 0; nj < 2; ++nj)
          acc[4 + fi][nj] = __builtin_amdgcn_mfma_f32_16x16x32_bf16(a1[fi * 2 + ks], be[nj * 2 + ks], acc[4 + fi][nj], 0, 0, 0);
    __builtin_amdgcn_s_setprio(0);

    // ---- phase 3 ----
    asm volatile("s_barrier" ::: "memory");
    STG_A02(bo, kk2);
    __builtin_amdgcn_s_setprio(1);
    #pragma unroll
    for (int ks = 0; ks < 2; ++ks)
      #pragma unroll
      for (int fi = 0; fi < 4; ++fi)
        #pragma unroll
        for (int nj = 0; nj < 2; ++nj)
          acc[4 + fi][2 + nj] = __builtin_amdgcn_mfma_f32_16x16x32_bf16(a1[fi * 2 + ks], bod[nj * 2 + ks], acc[4 + fi][2 + nj], 0, 0, 0);
    __builtin_amdgcn_s_setprio(0);
  }
#undef STG_A02
#undef STG_A13
#undef STG_BEV
#undef STG_BOD

  u16* Cz = C + (size_t)z * sC;
  #pragma unroll
  for (int mi = 0; mi < 8; ++mi)
    #pragma unroll
    for (int ni = 0; ni < 4; ++ni) {
      const size_t row = m0 + wm * 128 + (mi >> 2) * 64 + (mi & 3) * 16 + fq * 4;
      const size_t col = n0 + wn * 64 + (ni >> 1) * 32 + (ni & 1) * 16 + fr;
      #pragma unroll
      for (int r = 0; r < 4; ++r)
        Cz[(row + r) * ldc + col] = f2bf(acc[mi][ni][r] * scale);
    }
}

// ---------------- 128x256 8-phase bf16 GEMM (y), 3 LDS buffers, 1D grid ----------------
// XCD partition: xcd = p&7 owns by in [xcd*8, xcd*8+8): 8 A-panels (2MB) + all 4 B-panels (2MB) = 4MB/XCD.
__global__ __launch_bounds__(512, 2) void gemm8p128(
    const u16* __restrict__ A, int lda,
    const u16* __restrict__ Bt, int ldb,
    u16* __restrict__ C, int ldc,
    float scale, int K) {
  __shared__ char smem[147456];
  const int tid = threadIdx.x;
  const int wave = tid >> 6, lane = tid & 63;
  const int fr = lane & 15, fq = lane >> 4;
  const int wm = wave >> 2, wn = wave & 3;
  const int p = blockIdx.x;
  const int xcd = p & 7, sidx = p >> 3;
  const size_t m0 = (size_t)(xcd * 8 + (sidx >> 2)) * 128;
  const size_t n0 = (size_t)(sidx & 3) * 256;
  const u16* Ab = A + m0 * lda;
  const u16* Bb = Bt + n0 * ldb;
  const int perA = (lane >> 3) * lda + (((lane & 7) ^ (lane >> 3)) * 8);
  const int perB = (lane >> 3) * ldb + (((lane & 7) ^ (lane >> 3)) * 8);
  const int u0v = wave * 2, u1v = wave * 2 + 1;
  const int rA_0 = u0v * 8;
  const int rA_1 = u1v * 8;
  const int rB_0 = (u0v >> 2) * 64 + (u0v & 3) * 8;
  const int rB_1 = (u1v >> 2) * 64 + (u1v & 3) * 8;
  const int sw0 = ((fq) ^ (fr & 7)) * 16;
  const int sw1 = ((4 + fq) ^ (fr & 7)) * 16;
  const int aBase = wm * 8192 + fr * 128;
  const int bBase = 16384 + wn * 8192 + fr * 128;

  f32x4 acc[4][4];
  #pragma unroll
  for (int i = 0; i < 4; ++i)
    #pragma unroll
    for (int j = 0; j < 4; ++j) acc[i][j] = (f32x4)(0.0f);

#define STG_A(BUF, KK) do { \
    glds16(Ab + (size_t)rA_0 * lda + perA + (KK), smem + (BUF) + rA_0 * 128); \
    glds16(Ab + (size_t)rA_1 * lda + perA + (KK), smem + (BUF) + rA_1 * 128); } while (0)
#define STG_BEV(BUF, KK) do { \
    glds16(Bb + (size_t)rB_0 * ldb + perB + (KK), smem + (BUF) + 16384 + rB_0 * 128); \
    glds16(Bb + (size_t)rB_1 * ldb + perB + (KK), smem + (BUF) + 16384 + rB_1 * 128); } while (0)
#define STG_BOD(BUF, KK) do { \
    glds16(Bb + (size_t)(rB_0 + 32) * ldb + perB + (KK), smem + (BUF) + 16384 + (rB_0 + 32) * 128); \
    glds16(Bb + (size_t)(rB_1 + 32) * ldb + perB + (KK), smem + (BUF) + 16384 + (rB_1 + 32) * 128); } while (0)

  const int NT = K >> 6;
  STG_A(0, 0); STG_BEV(0, 0); STG_BOD(0, 0);
  {
    const int k1 = (NT > 1) ? 64 : 0;
    STG_A(49152, k1); STG_BEV(49152, k1); STG_BOD(49152, k1);
  }

  for (int t = 0; t < NT; ++t) {
    const int bo = (t % 3) * 49152;
    const int bs = ((t + 2) % 3) * 49152;
    const int kk = (t + 2 < NT) ? (t + 2) * 64 : 0;
    short8 af[8], bv[4];

    // ---- phase 0: nh0 ----
    asm volatile("s_waitcnt vmcnt(8)" ::: "memory");
    asm volatile("s_barrier" ::: "memory");
    #pragma unroll
    for (int fi = 0; fi < 4; ++fi) {
      af[fi * 2 + 0] = *(const short8*)(smem + bo + aBase + fi * 2048 + sw0);
      af[fi * 2 + 1] = *(const short8*)(smem + bo + aBase + fi * 2048 + sw1);
    }
    #pragma unroll
    for (int nj = 0; nj < 2; ++nj) {
      bv[nj * 2 + 0] = *(const short8*)(smem + bo + bBase + nj * 2048 + sw0);
      bv[nj * 2 + 1] = *(const short8*)(smem + bo + bBase + nj * 2048 + sw1);
    }
    STG_A(bs, kk);
    STG_BEV(bs, kk);
    __builtin_amdgcn_s_setprio(1);
    #pragma unroll
    for (int ks = 0; ks < 2; ++ks)
      #pragma unroll
      for (int fi = 0; fi < 4; ++fi)
        #pragma unroll
        for (int nj = 0; nj < 2; ++nj)
          acc[fi][nj] = __builtin_amdgcn_mfma_f32_16x16x32_bf16(af[fi * 2 + ks], bv[nj * 2 + ks], acc[fi][nj], 0, 0, 0);
    __builtin_amdgcn_s_setprio(0);

    // ---- phase 1: nh1 ----
    asm volatile("s_waitcnt vmcnt(10)" ::: "memory");
    asm volatile("s_barrier" ::: "memory");
    #pragma unroll
    for (int nj = 0; nj < 2; ++nj) {
      bv[nj * 2 + 0] = *(const short8*)(smem + bo + bBase + 4096 + nj * 2048 + sw0);
      bv[nj * 2 + 1] = *(const short8*)(smem + bo + bBase + 4096 + nj * 2048 + sw1);
    }
    STG_BOD(bs, kk);
    __builtin_amdgcn_s_setprio(1);
    #pragma unroll
    for (int ks = 0; ks < 2; ++ks)
      #pragma unroll
      for (int fi = 0; fi < 4; ++fi)
        #pragma unroll
        for (int nj = 0; nj < 2; ++nj)
          acc[fi][2 + nj] = __builtin_amdgcn_mfma_f32_16x16x32_bf16(af[fi * 2 + ks], bv[nj * 2 + ks], acc[fi][2 + nj], 0, 0, 0);
    __builtin_amdgcn_s_setprio(0);
  }
#undef STG_A
#undef STG_BEV
#undef STG_BOD

  #pragma unroll
  for (int fi = 0; fi < 4; ++fi)
    #pragma unroll
    for (int ni = 0; ni < 4; ++ni) {
      const size_t row = m0 + wm * 64 + fi * 16 + fq * 4;
      const size_t col = n0 + wn * 64 + (ni >> 1) * 32 + (ni & 1) * 16 + fr;
      #pragma unroll
      for (int r = 0; r < 4; ++r)
        C[(row + r) * ldc + col] = f2bf(acc[fi][ni][r] * scale);
    }
}

// ---------------- row softmax + prior transform; emits na row, ell, dvec ----------------
__global__ __launch_bounds__(256) void softmax_kernel(const u16* __restrict__ Sb,
                                                      const float* __restrict__ bvec,
                                                      const float* __restrict__ prior,
                                                      float* __restrict__ na,
                                                      float* __restrict__ ell,
                                                      float* __restrict__ dvec) {
  const int row = blockIdx.x;
  const int t = threadIdx.x;
  const int b = row >> 11, i = row & (S_LEN - 1);
  const short8 sv = ((const short8*)(Sb + (size_t)row * S_LEN))[t];
  const f32x4 bv0 = ((const f32x4*)(bvec + (size_t)b * S_LEN))[t * 2];
  const f32x4 bv1 = ((const f32x4*)(bvec + (size_t)b * S_LEN))[t * 2 + 1];
  float v[8];
  #pragma unroll
  for (int u = 0; u < 8; ++u)
    v[u] = bf2f((u16)sv[u]) + ((u < 4) ? bv0[u] : bv1[u - 4]);
  float mx = v[0];
  #pragma unroll
  for (int u = 1; u < 8; ++u) mx = fmaxf(mx, v[u]);
  for (int o = 32; o > 0; o >>= 1) mx = fmaxf(mx, __shfl_xor(mx, o));
  __shared__ float red[4], red2[4];
  const int wave = t >> 6, lane = t & 63;
  if (lane == 0) red[wave] = mx;
  __syncthreads();
  mx = fmaxf(fmaxf(red[0], red[1]), fmaxf(red[2], red[3]));
  float e[8], s = 0.0f;
  #pragma unroll
  for (int u = 0; u < 8; ++u) { e[u] = __expf(v[u] - mx); s += e[u]; }
  for (int o = 32; o > 0; o >>= 1) s += __shfl_xor(s, o);
  if (lane == 0) red2[wave] = s;
  __syncthreads();
  s = red2[0] + red2[1] + red2[2] + red2[3];
  const float pr = prior[0];
  const float w = 1.0f - pr;
  const float inv = 1.0f / s;
  f32x4 o0, o1;
  #pragma unroll
  for (int u = 0; u < 4; ++u) o0[u] = pr + w * (e[u] * inv + 1e-9f);
  #pragma unroll
  for (int u = 0; u < 4; ++u) o1[u] = pr + w * (e[4 + u] * inv + 1e-9f);
  f32x4* nrow = (f32x4*)(na + (size_t)row * S_LEN);
  nrow[t * 2] = o0;
  nrow[t * 2 + 1] = o1;
  #pragma unroll
  for (int u = 0; u < 8; ++u) {
    const int j = t * 8 + u;
    const float ov = (u < 4) ? o0[u] : o1[u - 4];
    if (j == i) dvec[row] = ov;
    if (j == i + 1) ell[row] = logf(ov + 1e-9f);
  }
  if (i == S_LEN - 1 && t == 0) ell[row] = 0.0f;
}

// ---------------- exclusive prefix sum of ell -> Cpre ----------------
__global__ __launch_bounds__(256) void scan_kernel(const float* __restrict__ ell,
                                                   float* __restrict__ Cpre) {
  const int b = blockIdx.x, t = threadIdx.x;
  const float* eb = ell + (size_t)b * S_LEN;
  const f32x4 e0 = ((const f32x4*)eb)[t * 2];
  const f32x4 e1 = ((const f32x4*)eb)[t * 2 + 1];
  float ev[8];
  #pragma unroll
  for (int u = 0; u < 4; ++u) ev[u] = e0[u];
  #pragma unroll
  for (int u = 0; u < 4; ++u) ev[4 + u] = e1[u];
  float loc[8], tot = 0.0f;
  #pragma unroll
  for (int u = 0; u < 8; ++u) { loc[u] = tot; tot += ev[u]; }
  __shared__ float sbuf[256];
  sbuf[t] = tot;
  __syncthreads();
  for (int off = 1; off < 256; off <<= 1) {
    const float v = (t >= off) ? sbuf[t - off] : 0.0f;
    __syncthreads();
    sbuf[t] += v;
    __syncthreads();
  }
  const float base = (t == 0) ? 0.0f : sbuf[t - 1];
  #pragma unroll
  for (int u = 0; u < 8; ++u)
    Cpre[(size_t)b * S_LEN + t * 8 + u] = base + loc[u];
}

// ---------------- g_attn: exp(C[max]-C[min]) + 1e-9, diag from dvec; one block per row ----------------
__global__ __launch_bounds__(256) void gattn_kernel(const float* __restrict__ Cpre,
                                                    const float* __restrict__ dvec,
                                                    float* __restrict__ g) {
  const int b = blockIdx.y, i = blockIdx.x;
  const int t = threadIdx.x;
  const float Ci = Cpre[b * S_LEN + i];
  const float di = dvec[b * S_LEN + i];
  float* grow = g + ((size_t)b * S_LEN + i) * S_LEN;
  #pragma unroll
  for (int h = 0; h < 2; ++h) {
    const int j0 = h * 1024 + t * 4;
    const f32x4 Cj = *(const f32x4*)&Cpre[b * S_LEN + j0];
    f32x4 o;
    #pragma unroll
    for (int u = 0; u < 4; ++u) {
      const int j = j0 + u;
      const float arg = (j > i) ? (Cj[u] - Ci) : (Ci - Cj[u]);
      o[u] = (j == i) ? (di + 1e-9f) : (__expf(arg) + 1e-9f);
    }
    *(f32x4*)(grow + j0) = o;
  }
}

extern "C" void kernel_launch(void* const* d_in, const int* in_sizes, int n_in,
                              void* d_out, int out_size, void* d_ws, size_t ws_size,
                              hipStream_t stream) {
  const float* ctx   = (const float*)d_in[0];
  // d_in[1] = eos_mask: numerically a no-op (mask * 1e-19 in fp32), never read.
  const float* prior = (const float*)d_in[2];
  const float* gamma = (const float*)d_in[3];
  const float* beta  = (const float*)d_in[4];
  const float* Wk    = (const float*)d_in[5];
  const float* Wq    = (const float*)d_in[7];
  const float* bq    = (const float*)d_in[8];

  float* g  = (float*)d_out;                               // g_attn output (also bf16 scores scratch)
  float* na = g + (size_t)NB * S_LEN * S_LEN;              // neibor_attn output

  // scratch inside the na output region (all dead before softmax overwrites it):
  u16* Xb = (u16*)na;                                              // [8192][1024] bf16 (16 MiB)
  u16* Yb = Xb + (size_t)(NB * S_LEN) * D_MODEL;                   // [8192][1024] bf16 (16 MiB)
  u16* PT = Yb + (size_t)(NB * S_LEN) * D_MODEL;                   // [1024][1024] bf16 (2 MiB)
  u16* Wt = PT + (size_t)D_MODEL * D_MODEL;                        // [2048][1024] bf16 (4 MiB)
  // bf16 scores live in the g output region (overwritten by gattn at the end):
  u16* Sb = (u16*)g;                                               // [8192][2048] bf16 (32 MiB)
  // small scratch in ws:
  float* w2   = (float*)d_ws;                                      // [1024]
  float* bvec = w2 + D_MODEL;                                      // [8192]
  float* ell  = bvec + NB * S_LEN;                                 // [8192]
  float* dvec = ell + NB * S_LEN;                                  // [8192]
  float* Cpre = dvec + NB * S_LEN;                                 // [8192]

  prep_w<<<dim3(32, 65), dim3(32, 8), 0, stream>>>(Wq, Wk, bq, Wt, w2);
  ln_kernel<<<NB * S_LEN, 256, 0, stream>>>(ctx, gamma, beta, w2, Xb, bvec);

  // PT[n][k] = P[k][n], P = Wq·Wk^T  ->  PT = gemm(A=Wk^T, Bt=Wq^T)
  gemm_bt<<<dim3(8, 8, 1), 256, 0, stream>>>(Wt + (size_t)D_MODEL * D_MODEL, D_MODEL, 0,
                                             Wt, D_MODEL, 0,
                                             PT, D_MODEL, 0, 1.0f, D_MODEL);
  // y = x·P  ->  deep 3-buffer 8-phase BM=128 variant, 256 blocks, XCD-partitioned
  gemm8p128<<<256, 512, 0, stream>>>(Xb, D_MODEL,
                                     PT, D_MODEL,
                                     Yb, D_MODEL, 1.0f, D_MODEL);
  // scores[b] = (y[b] · x[b]^T) / d  (bf16 out) — 256² 8-phase kernel, XCD-partitioned
  gemm8p256<<<256, 512, 0, stream>>>(Yb, D_MODEL, (long long)S_LEN * D_MODEL,
                                     Xb, D_MODEL, (long long)S_LEN * D_MODEL,
                                     Sb, S_LEN, (long long)S_LEN * S_LEN,
                                     1.0f / (float)D_MODEL, D_MODEL);

  softmax_kernel<<<NB * S_LEN, 256, 0, stream>>>(Sb, bvec, prior, na, ell, dvec);
  scan_kernel<<<NB, 256, 0, stream>>>(ell, Cpre);
  gattn_kernel<<<dim3(S_LEN, NB), 256, 0, stream>>>(Cpre, dvec, g);
}

// Round 8
// 123.812 us; speedup vs baseline: 1.1325x; 1.1325x over previous
//
#include <hip/hip_runtime.h>
#include <hip/hip_fp8.h>

#define S_LEN 2048
#define D_MODEL 1024
#define NB 4

typedef unsigned short u16;
typedef __attribute__((ext_vector_type(8))) short short8;
typedef __attribute__((ext_vector_type(4))) float f32x4;
typedef __attribute__((ext_vector_type(16))) float f32x16;
typedef __attribute__((ext_vector_type(4))) unsigned short u16x4;
typedef __attribute__((ext_vector_type(4))) int i32x4;
typedef __attribute__((ext_vector_type(8))) int i32x8;

__device__ inline u16 f2bf(float f) {
  union { float f; unsigned u; } v; v.f = f;
  unsigned u = v.u;
  unsigned r = (u + 0x7FFFu + ((u >> 16) & 1u)) >> 16;
  return (u16)r;
}

__device__ inline float bf2f(u16 b) {
  union { unsigned u; float f; } v; v.u = ((unsigned)b) << 16;
  return v.f;
}

__device__ inline unsigned char f2e4m3(float f) {
  __hip_fp8_e4m3 q(f);
  return (unsigned char)q.__x;
}

__device__ inline void glds16(const void* g, void* l) {
  __builtin_amdgcn_global_load_lds((const __attribute__((address_space(1))) void*)g,
                                   (__attribute__((address_space(3))) void*)l,
                                   16, 0, 0);
}

__device__ inline i32x8 cat8(i32x4 a, i32x4 b) {
  i32x8 r;
  r[0] = a[0]; r[1] = a[1]; r[2] = a[2]; r[3] = a[3];
  r[4] = b[0]; r[5] = b[1]; r[6] = b[2]; r[7] = b[3];
  return r;
}

// ---------------- w2[t] = sum_n Wk[t][n] * bq[n]  (one wave per row) ----------------
__global__ __launch_bounds__(256) void w2_kernel(const float* __restrict__ Wk,
                                                 const float* __restrict__ bq,
                                                 float* __restrict__ w2) {
  const int r = blockIdx.x * 4 + (threadIdx.x >> 6);
  const int lane = threadIdx.x & 63;
  const f32x4* row = (const f32x4*)(Wk + (size_t)r * D_MODEL);
  float s = 0.0f;
  #pragma unroll
  for (int c = 0; c < 4; ++c) {
    const f32x4 v = row[lane * 4 + c];
    const f32x4 b = ((const f32x4*)bq)[lane * 4 + c];
    s += v[0]*b[0] + v[1]*b[1] + v[2]*b[2] + v[3]*b[3];
  }
  for (int o = 32; o > 0; o >>= 1) s += __shfl_xor(s, o);
  if (lane == 0) w2[r] = s;
}

// ---------------- LayerNorm: fp32 in -> bf16 Xb + fp8 X8 + fused bvec ----------------
__global__ __launch_bounds__(256) void ln_kernel(const float* __restrict__ ctx,
                                                 const float* __restrict__ gamma,
                                                 const float* __restrict__ beta,
                                                 const float* __restrict__ w2,
                                                 u16* __restrict__ xb,
                                                 unsigned char* __restrict__ x8,
                                                 float* __restrict__ bvec) {
  const int row = blockIdx.x;
  const int t = threadIdx.x;
  const f32x4 v = ((const f32x4*)(ctx + (size_t)row * D_MODEL))[t];
  float s = v[0] + v[1] + v[2] + v[3];
  float q = v[0]*v[0] + v[1]*v[1] + v[2]*v[2] + v[3]*v[3];
  for (int o = 32; o > 0; o >>= 1) { s += __shfl_xor(s, o); q += __shfl_xor(q, o); }
  __shared__ float rs[4], rq[4], rd[4];
  const int wave = t >> 6, lane = t & 63;
  if (lane == 0) { rs[wave] = s; rq[wave] = q; }
  __syncthreads();
  s = rs[0] + rs[1] + rs[2] + rs[3];
  q = rq[0] + rq[1] + rq[2] + rq[3];
  const float mu = s * (1.0f / D_MODEL);
  const float var = q * (1.0f / D_MODEL) - mu * mu;
  const float rstd = rsqrtf(var + 1e-3f);
  const f32x4 g4 = ((const f32x4*)gamma)[t];
  const f32x4 b4 = ((const f32x4*)beta)[t];
  const f32x4 w4 = ((const f32x4*)w2)[t];
  float xv[4];
  float dot = 0.0f;
  #pragma unroll
  for (int u = 0; u < 4; ++u) {
    xv[u] = (v[u] - mu) * rstd * g4[u] + b4[u];
    dot += xv[u] * w4[u];
  }
  u16x4 o;
  #pragma unroll
  for (int u = 0; u < 4; ++u) o[u] = f2bf(xv[u]);
  ((u16x4*)(xb + (size_t)row * D_MODEL))[t] = o;
  unsigned pk = (unsigned)f2e4m3(xv[0]) | ((unsigned)f2e4m3(xv[1]) << 8) |
                ((unsigned)f2e4m3(xv[2]) << 16) | ((unsigned)f2e4m3(xv[3]) << 24);
  ((unsigned*)(x8 + (size_t)row * D_MODEL))[t] = pk;
  for (int of = 32; of > 0; of >>= 1) dot += __shfl_xor(dot, of);
  if (lane == 0) rd[wave] = dot;
  __syncthreads();
  if (t == 0) bvec[row] = (rd[0] + rd[1] + rd[2] + rd[3]) * (1.0f / D_MODEL);
}

// ---------------- weight prep: Wt[n][k] = bf16(W[k][n]); rows [0,1024)=Wq^T, [1024,2048)=Wk^T ----------------
__global__ __launch_bounds__(256) void prep_w(const float* __restrict__ Wq,
                                              const float* __restrict__ Wk,
                                              u16* __restrict__ Wt) {
  __shared__ float tile[32][33];
  const int k0 = blockIdx.x * 32;
  const int n0 = blockIdx.y * 32;
  const int tx = threadIdx.x, ty = threadIdx.y;
  const float* W = (n0 < D_MODEL) ? Wq : Wk;
  const int nl0 = (n0 < D_MODEL) ? n0 : (n0 - D_MODEL);
  #pragma unroll
  for (int j = 0; j < 32; j += 8)
    tile[ty + j][tx] = W[(size_t)(k0 + ty + j) * D_MODEL + nl0 + tx];
  __syncthreads();
  #pragma unroll
  for (int j = 0; j < 32; j += 8)
    Wt[(size_t)(n0 + ty + j) * D_MODEL + k0 + tx] = f2bf(tile[tx][ty + j]);
}

// ---------------- bf16 GEMM: m97-style 128x128 tile (PT only) ----------------
__global__ __launch_bounds__(256, 2) void gemm_bt(
    const u16* __restrict__ A, int lda,
    const u16* __restrict__ Bt, int ldb,
    u16* __restrict__ C, int ldc,
    float scale, int K) {
  __shared__ u16 As[128][32];
  __shared__ u16 Bs[128][32];
  const int tid = threadIdx.x;
  const int wave = tid >> 6, lane = tid & 63;
  const size_t m0 = (size_t)blockIdx.y * 128;
  const size_t n0 = (size_t)blockIdx.x * 128;
  const int wr = (wave >> 1) * 64;
  const int wc = (wave & 1) * 64;
  const int strow = wave * 16 + (lane >> 2);
  const int stslot = (lane & 3) * 8;
  const int fr = lane & 15, fq = lane >> 4;

  f32x4 acc[4][4];
  #pragma unroll
  for (int i = 0; i < 4; ++i)
    #pragma unroll
    for (int j = 0; j < 4; ++j) acc[i][j] = (f32x4)(0.0f);

  for (int k0 = 0; k0 < K; k0 += 32) {
    const u16* ga = A + (m0 + strow) * lda + k0 + stslot;
    const u16* gb = Bt + (n0 + strow) * ldb + k0 + stslot;
    glds16(ga, &As[wave * 16][0]);
    glds16(ga + (size_t)64 * lda, &As[64 + wave * 16][0]);
    glds16(gb, &Bs[wave * 16][0]);
    glds16(gb + (size_t)64 * ldb, &Bs[64 + wave * 16][0]);
    __syncthreads();
    short8 af[4], bfv[4];
    #pragma unroll
    for (int mi = 0; mi < 4; ++mi) af[mi] = *(const short8*)&As[wr + mi * 16 + fr][fq * 8];
    #pragma unroll
    for (int ni = 0; ni < 4; ++ni) bfv[ni] = *(const short8*)&Bs[wc + ni * 16 + fr][fq * 8];
    #pragma unroll
    for (int mi = 0; mi < 4; ++mi)
      #pragma unroll
      for (int ni = 0; ni < 4; ++ni)
        acc[mi][ni] = __builtin_amdgcn_mfma_f32_16x16x32_bf16(af[mi], bfv[ni], acc[mi][ni], 0, 0, 0);
    __syncthreads();
  }

  #pragma unroll
  for (int mi = 0; mi < 4; ++mi)
    #pragma unroll
    for (int ni = 0; ni < 4; ++ni) {
      const size_t row = m0 + wr + mi * 16 + fq * 4;
      const size_t col = n0 + wc + ni * 16 + fr;
      #pragma unroll
      for (int r = 0; r < 4; ++r)
        C[(row + r) * ldc + col] = f2bf(acc[mi][ni][r] * scale);
    }
}

// ---------------- 128x256 8-phase bf16 GEMM (y), 2 LDS buffers, fp8 output ----------------
// r5-proven schedule: p0: vmcnt(2); barrier; ds_read A(8)+Bev(4); stage A+Bev(t+1); 16 MFMA.
//                     p1: vmcnt(4); barrier; ds_read Bod(4); stage Bod(t+1); 16 MFMA.
__global__ __launch_bounds__(512, 2) void gemm8p128(
    const u16* __restrict__ A, int lda,
    const u16* __restrict__ Bt, int ldb,
    unsigned char* __restrict__ C8, int ldc,
    float scale, int K) {
  __shared__ char smem[98304];
  const int tid = threadIdx.x;
  const int wave = tid >> 6, lane = tid & 63;
  const int fr = lane & 15, fq = lane >> 4;
  const int wm = wave >> 2, wn = wave & 3;
  const size_t m0 = (size_t)blockIdx.y * 128;
  const size_t n0 = (size_t)blockIdx.x * 256;
  const u16* Ab = A + m0 * lda;
  const u16* Bb = Bt + n0 * ldb;
  const int perA = (lane >> 3) * lda + (((lane & 7) ^ (lane >> 3)) * 8);
  const int perB = (lane >> 3) * ldb + (((lane & 7) ^ (lane >> 3)) * 8);
  const int u0v = wave * 2, u1v = wave * 2 + 1;
  const int rA_0 = u0v * 8;
  const int rA_1 = u1v * 8;
  const int rB_0 = (u0v >> 2) * 64 + (u0v & 3) * 8;
  const int rB_1 = (u1v >> 2) * 64 + (u1v & 3) * 8;
  const int sw0 = ((fq) ^ (fr & 7)) * 16;
  const int sw1 = ((4 + fq) ^ (fr & 7)) * 16;
  const int aBase = wm * 8192 + fr * 128;
  const int bBase = 16384 + wn * 8192 + fr * 128;

  f32x4 acc[4][4];
  #pragma unroll
  for (int i = 0; i < 4; ++i)
    #pragma unroll
    for (int j = 0; j < 4; ++j) acc[i][j] = (f32x4)(0.0f);

#define STG_A(BUF, KK) do { \
    glds16(Ab + (size_t)rA_0 * lda + perA + (KK), smem + (BUF) + rA_0 * 128); \
    glds16(Ab + (size_t)rA_1 * lda + perA + (KK), smem + (BUF) + rA_1 * 128); } while (0)
#define STG_BEV(BUF, KK) do { \
    glds16(Bb + (size_t)rB_0 * ldb + perB + (KK), smem + (BUF) + 16384 + rB_0 * 128); \
    glds16(Bb + (size_t)rB_1 * ldb + perB + (KK), smem + (BUF) + 16384 + rB_1 * 128); } while (0)
#define STG_BOD(BUF, KK) do { \
    glds16(Bb + (size_t)(rB_0 + 32) * ldb + perB + (KK), smem + (BUF) + 16384 + (rB_0 + 32) * 128); \
    glds16(Bb + (size_t)(rB_1 + 32) * ldb + perB + (KK), smem + (BUF) + 16384 + (rB_1 + 32) * 128); } while (0)

  const int NT = K >> 6;
  STG_A(0, 0); STG_BEV(0, 0); STG_BOD(0, 0);

  for (int t = 0; t < NT; ++t) {
    const int bo = (t & 1) * 49152;
    const int bn = bo ^ 49152;
    const int kk = (t + 1 < NT) ? (t + 1) * 64 : 0;
    short8 af[8], bv[4];

    // ---- phase 0: nh0 ----
    asm volatile("s_waitcnt vmcnt(2)" ::: "memory");
    asm volatile("s_barrier" ::: "memory");
    #pragma unroll
    for (int fi = 0; fi < 4; ++fi) {
      af[fi * 2 + 0] = *(const short8*)(smem + bo + aBase + fi * 2048 + sw0);
      af[fi * 2 + 1] = *(const short8*)(smem + bo + aBase + fi * 2048 + sw1);
    }
    #pragma unroll
    for (int nj = 0; nj < 2; ++nj) {
      bv[nj * 2 + 0] = *(const short8*)(smem + bo + bBase + nj * 2048 + sw0);
      bv[nj * 2 + 1] = *(const short8*)(smem + bo + bBase + nj * 2048 + sw1);
    }
    STG_A(bn, kk);
    STG_BEV(bn, kk);
    __builtin_amdgcn_s_setprio(1);
    #pragma unroll
    for (int ks = 0; ks < 2; ++ks)
      #pragma unroll
      for (int fi = 0; fi < 4; ++fi)
        #pragma unroll
        for (int nj = 0; nj < 2; ++nj)
          acc[fi][nj] = __builtin_amdgcn_mfma_f32_16x16x32_bf16(af[fi * 2 + ks], bv[nj * 2 + ks], acc[fi][nj], 0, 0, 0);
    __builtin_amdgcn_s_setprio(0);

    // ---- phase 1: nh1 ----
    asm volatile("s_waitcnt vmcnt(4)" ::: "memory");
    asm volatile("s_barrier" ::: "memory");
    #pragma unroll
    for (int nj = 0; nj < 2; ++nj) {
      bv[nj * 2 + 0] = *(const short8*)(smem + bo + bBase + 4096 + nj * 2048 + sw0);
      bv[nj * 2 + 1] = *(const short8*)(smem + bo + bBase + 4096 + nj * 2048 + sw1);
    }
    STG_BOD(bn, kk);
    __builtin_amdgcn_s_setprio(1);
    #pragma unroll
    for (int ks = 0; ks < 2; ++ks)
      #pragma unroll
      for (int fi = 0; fi < 4; ++fi)
        #pragma unroll
        for (int nj = 0; nj < 2; ++nj)
          acc[fi][2 + nj] = __builtin_amdgcn_mfma_f32_16x16x32_bf16(af[fi * 2 + ks], bv[nj * 2 + ks], acc[fi][2 + nj], 0, 0, 0);
    __builtin_amdgcn_s_setprio(0);
  }
#undef STG_A
#undef STG_BEV
#undef STG_BOD

  #pragma unroll
  for (int fi = 0; fi < 4; ++fi)
    #pragma unroll
    for (int ni = 0; ni < 4; ++ni) {
      const size_t row = m0 + wm * 64 + fi * 16 + fq * 4;
      const size_t col = n0 + wn * 64 + (ni >> 1) * 32 + (ni & 1) * 16 + fr;
      #pragma unroll
      for (int r = 0; r < 4; ++r)
        C8[(row + r) * ldc + col] = f2e4m3(acc[fi][ni][r] * scale);
    }
}

// ---------------- 256x256 fp8 GEMM (scores): mfma_scale 32x32x64, BK=128, 8 waves ----------------
// LDS: 2 buf x (A 256x128B + B 256x128B) = 128 KiB. Swizzle: 16B slot ^= (row&7); 128B rows = 32 banks.
// 4 phases/K-tile (ks x nt-half), 4 MFMA each; staging 4 glds/wave at p0/p1 for tile t+1;
// single vmcnt(0) per tile at p0 drains loads issued 3-4 phases earlier.
__global__ __launch_bounds__(512, 2) void gemm8pF8(
    const unsigned char* __restrict__ A8, long long sA,
    const unsigned char* __restrict__ B8, long long sB,
    u16* __restrict__ C, int ldc, long long sC,
    float scale, int K) {
  __shared__ char smem[131072];
  const int tid = threadIdx.x;
  const int wave = tid >> 6, lane = tid & 63;
  const int wm = wave >> 2, wn = wave & 3;
  const int z = blockIdx.z;
  const size_t m0 = (size_t)blockIdx.y * 256;
  const size_t n0 = (size_t)blockIdx.x * 256;
  const unsigned char* Ab = A8 + (size_t)z * sA + m0 * K;
  const unsigned char* Bb = B8 + (size_t)z * sB + n0 * K;
  // staging: chunk = 8 rows x 128B; per-lane src offset
  const int perL = (lane >> 3) * K + (((lane & 7) ^ (lane >> 3)) * 16);
  const int w4 = wave * 4;
  // fragment read swizzle
  const int r7l = lane & 7;
  const int hi = lane >> 5;
  const int l31 = lane & 31;
  const int swk0_0 = ((hi * 2) ^ r7l) * 16;
  const int swk0_1 = ((hi * 2 + 1) ^ r7l) * 16;
  const int swk1_0 = ((4 + hi * 2) ^ r7l) * 16;
  const int swk1_1 = ((4 + hi * 2 + 1) ^ r7l) * 16;
  const int aOff = wm * 16384 + l31 * 128;          // + mt*4096 + sw
  const int bOff = 32768 + wn * 8192 + l31 * 128;   // + nt*4096 + sw

  f32x16 acc[4][2];
  #pragma unroll
  for (int i = 0; i < 4; ++i)
    #pragma unroll
    for (int j = 0; j < 2; ++j) acc[i][j] = (f32x16)(0.0f);

#define STG_A8(BUF, KK, C0) do { \
    glds16(Ab + (size_t)((w4 + (C0)) * 8) * K + perL + (KK), smem + (BUF) + (w4 + (C0)) * 1024); \
    glds16(Ab + (size_t)((w4 + (C0) + 1) * 8) * K + perL + (KK), smem + (BUF) + (w4 + (C0) + 1) * 1024); } while (0)
#define STG_B8(BUF, KK, C0) do { \
    glds16(Bb + (size_t)((w4 + (C0)) * 8) * K + perL + (KK), smem + (BUF) + 32768 + (w4 + (C0)) * 1024); \
    glds16(Bb + (size_t)((w4 + (C0) + 1) * 8) * K + perL + (KK), smem + (BUF) + 32768 + (w4 + (C0) + 1) * 1024); } while (0)

  const int NT = K >> 7;  // BK=128
  // prologue: stage tile 0 fully into buf0 (8 glds/wave)
  STG_A8(0, 0, 0); STG_A8(0, 0, 2); STG_B8(0, 0, 0); STG_B8(0, 0, 2);

  for (int t = 0; t < NT; ++t) {
    const int bo = (t & 1) * 65536;
    const int bn = bo ^ 65536;
    const int kk = (t + 1 < NT) ? (t + 1) * 128 : 0;
    i32x8 afr[4], bfr[2];

    // ---- phase 0: ks0, nt0 ----
    asm volatile("s_waitcnt vmcnt(0)" ::: "memory");
    asm volatile("s_barrier" ::: "memory");
    #pragma unroll
    for (int mt = 0; mt < 4; ++mt)
      afr[mt] = cat8(*(const i32x4*)(smem + bo + aOff + mt * 4096 + swk0_0),
                     *(const i32x4*)(smem + bo + aOff + mt * 4096 + swk0_1));
    bfr[0] = cat8(*(const i32x4*)(smem + bo + bOff + swk0_0),
                  *(const i32x4*)(smem + bo + bOff + swk0_1));
    STG_A8(bn, kk, 0); STG_B8(bn, kk, 0);
    __builtin_amdgcn_s_setprio(1);
    #pragma unroll
    for (int mt = 0; mt < 4; ++mt)
      acc[mt][0] = __builtin_amdgcn_mfma_scale_f32_32x32x64_f8f6f4(
          afr[mt], bfr[0], acc[mt][0], 0, 0, 0, 0x7F7F7F7F, 0, 0x7F7F7F7F);
    __builtin_amdgcn_s_setprio(0);

    // ---- phase 1: ks0, nt1 ----
    asm volatile("s_barrier" ::: "memory");
    bfr[1] = cat8(*(const i32x4*)(smem + bo + bOff + 4096 + swk0_0),
                  *(const i32x4*)(smem + bo + bOff + 4096 + swk0_1));
    STG_A8(bn, kk, 2); STG_B8(bn, kk, 2);
    __builtin_amdgcn_s_setprio(1);
    #pragma unroll
    for (int mt = 0; mt < 4; ++mt)
      acc[mt][1] = __builtin_amdgcn_mfma_scale_f32_32x32x64_f8f6f4(
          afr[mt], bfr[1], acc[mt][1], 0, 0, 0, 0x7F7F7F7F, 0, 0x7F7F7F7F);
    __builtin_amdgcn_s_setprio(0);

    // ---- phase 2: ks1, nt0 ----
    asm volatile("s_barrier" ::: "memory");
    #pragma unroll
    for (int mt = 0; mt < 4; ++mt)
      afr[mt] = cat8(*(const i32x4*)(smem + bo + aOff + mt * 4096 + swk1_0),
                     *(const i32x4*)(smem + bo + aOff + mt * 4096 + swk1_1));
    bfr[0] = cat8(*(const i32x4*)(smem + bo + bOff + swk1_0),
                  *(const i32x4*)(smem + bo + bOff + swk1_1));
    __builtin_amdgcn_s_setprio(1);
    #pragma unroll
    for (int mt = 0; mt < 4; ++mt)
      acc[mt][0] = __builtin_amdgcn_mfma_scale_f32_32x32x64_f8f6f4(
          afr[mt], bfr[0], acc[mt][0], 0, 0, 0, 0x7F7F7F7F, 0, 0x7F7F7F7F);
    __builtin_amdgcn_s_setprio(0);

    // ---- phase 3: ks1, nt1 ----
    asm volatile("s_barrier" ::: "memory");
    bfr[1] = cat8(*(const i32x4*)(smem + bo + bOff + 4096 + swk1_0),
                  *(const i32x4*)(smem + bo + bOff + 4096 + swk1_1));
    __builtin_amdgcn_s_setprio(1);
    #pragma unroll
    for (int mt = 0; mt < 4; ++mt)
      acc[mt][1] = __builtin_amdgcn_mfma_scale_f32_32x32x64_f8f6f4(
          afr[mt], bfr[1], acc[mt][1], 0, 0, 0, 0x7F7F7F7F, 0, 0x7F7F7F7F);
    __builtin_amdgcn_s_setprio(0);
  }
#undef STG_A8
#undef STG_B8

  // C/D layout 32x32: col = lane&31, row = (r&3) + 8*(r>>2) + 4*(lane>>5)
  u16* Cz = C + (size_t)z * sC;
  #pragma unroll
  for (int mt = 0; mt < 4; ++mt)
    #pragma unroll
    for (int nt = 0; nt < 2; ++nt) {
      const size_t colg = n0 + wn * 64 + nt * 32 + l31;
      #pragma unroll
      for (int r = 0; r < 16; ++r) {
        const size_t rowg = m0 + wm * 128 + mt * 32 + (r & 3) + 8 * (r >> 2) + 4 * hi;
        Cz[rowg * ldc + colg] = f2bf(acc[mt][nt][r] * scale);
      }
    }
}

// ---------------- row softmax + prior transform; emits na row, ell, dvec ----------------
__global__ __launch_bounds__(256) void softmax_kernel(const u16* __restrict__ Sb,
                                                      const float* __restrict__ bvec,
                                                      const float* __restrict__ prior,
                                                      float* __restrict__ na,
                                                      float* __restrict__ ell,
                                                      float* __restrict__ dvec) {
  const int row = blockIdx.x;
  const int t = threadIdx.x;
  const int b = row >> 11, i = row & (S_LEN - 1);
  const short8 sv = ((const short8*)(Sb + (size_t)row * S_LEN))[t];
  const f32x4 bv0 = ((const f32x4*)(bvec + (size_t)b * S_LEN))[t * 2];
  const f32x4 bv1 = ((const f32x4*)(bvec + (size_t)b * S_LEN))[t * 2 + 1];
  float v[8];
  #pragma unroll
  for (int u = 0; u < 8; ++u)
    v[u] = bf2f((u16)sv[u]) + ((u < 4) ? bv0[u] : bv1[u - 4]);
  float mx = v[0];
  #pragma unroll
  for (int u = 1; u < 8; ++u) mx = fmaxf(mx, v[u]);
  for (int o = 32; o > 0; o >>= 1) mx = fmaxf(mx, __shfl_xor(mx, o));
  __shared__ float red[4], red2[4];
  const int wave = t >> 6, lane = t & 63;
  if (lane == 0) red[wave] = mx;
  __syncthreads();
  mx = fmaxf(fmaxf(red[0], red[1]), fmaxf(red[2], red[3]));
  float e[8], s = 0.0f;
  #pragma unroll
  for (int u = 0; u < 8; ++u) { e[u] = __expf(v[u] - mx); s += e[u]; }
  for (int o = 32; o > 0; o >>= 1) s += __shfl_xor(s, o);
  if (lane == 0) red2[wave] = s;
  __syncthreads();
  s = red2[0] + red2[1] + red2[2] + red2[3];
  const float pr = prior[0];
  const float w = 1.0f - pr;
  const float inv = 1.0f / s;
  f32x4 o0, o1;
  #pragma unroll
  for (int u = 0; u < 4; ++u) o0[u] = pr + w * (e[u] * inv + 1e-9f);
  #pragma unroll
  for (int u = 0; u < 4; ++u) o1[u] = pr + w * (e[4 + u] * inv + 1e-9f);
  f32x4* nrow = (f32x4*)(na + (size_t)row * S_LEN);
  nrow[t * 2] = o0;
  nrow[t * 2 + 1] = o1;
  #pragma unroll
  for (int u = 0; u < 8; ++u) {
    const int j = t * 8 + u;
    const float ov = (u < 4) ? o0[u] : o1[u - 4];
    if (j == i) dvec[row] = ov;
    if (j == i + 1) ell[row] = logf(ov + 1e-9f);
  }
  if (i == S_LEN - 1 && t == 0) ell[row] = 0.0f;
}

// ---------------- exclusive prefix sum of ell -> Cpre ----------------
__global__ __launch_bounds__(256) void scan_kernel(const float* __restrict__ ell,
                                                   float* __restrict__ Cpre) {
  const int b = blockIdx.x, t = threadIdx.x;
  const float* eb = ell + (size_t)b * S_LEN;
  const f32x4 e0 = ((const f32x4*)eb)[t * 2];
  const f32x4 e1 = ((const f32x4*)eb)[t * 2 + 1];
  float ev[8];
  #pragma unroll
  for (int u = 0; u < 4; ++u) ev[u] = e0[u];
  #pragma unroll
  for (int u = 0; u < 4; ++u) ev[4 + u] = e1[u];
  float loc[8], tot = 0.0f;
  #pragma unroll
  for (int u = 0; u < 8; ++u) { loc[u] = tot; tot += ev[u]; }
  __shared__ float sbuf[256];
  sbuf[t] = tot;
  __syncthreads();
  for (int off = 1; off < 256; off <<= 1) {
    const float v = (t >= off) ? sbuf[t - off] : 0.0f;
    __syncthreads();
    sbuf[t] += v;
    __syncthreads();
  }
  const float base = (t == 0) ? 0.0f : sbuf[t - 1];
  #pragma unroll
  for (int u = 0; u < 8; ++u)
    Cpre[(size_t)b * S_LEN + t * 8 + u] = base + loc[u];
}

// ---------------- g_attn: exp(C[max]-C[min]) + 1e-9, diag from dvec ----------------
__global__ __launch_bounds__(256) void gattn_kernel(const float* __restrict__ Cpre,
                                                    const float* __restrict__ dvec,
                                                    float* __restrict__ g) {
  const int b = blockIdx.z, i = blockIdx.y;
  const int j0 = blockIdx.x * 1024 + threadIdx.x * 4;
  const float Ci = Cpre[b * S_LEN + i];
  const float di = dvec[b * S_LEN + i];
  const f32x4 Cj = *(const f32x4*)&Cpre[b * S_LEN + j0];
  f32x4 o;
  #pragma unroll
  for (int u = 0; u < 4; ++u) {
    const int j = j0 + u;
    const float arg = (j > i) ? (Cj[u] - Ci) : (Ci - Cj[u]);
    o[u] = (j == i) ? (di + 1e-9f) : (__expf(arg) + 1e-9f);
  }
  *(f32x4*)(g + ((size_t)b * S_LEN + i) * S_LEN + j0) = o;
}

extern "C" void kernel_launch(void* const* d_in, const int* in_sizes, int n_in,
                              void* d_out, int out_size, void* d_ws, size_t ws_size,
                              hipStream_t stream) {
  const float* ctx   = (const float*)d_in[0];
  // d_in[1] = eos_mask: numerically a no-op (mask * 1e-19 in fp32), never read.
  const float* prior = (const float*)d_in[2];
  const float* gamma = (const float*)d_in[3];
  const float* beta  = (const float*)d_in[4];
  const float* Wk    = (const float*)d_in[5];
  const float* Wq    = (const float*)d_in[7];
  const float* bq    = (const float*)d_in[8];

  float* g  = (float*)d_out;                               // g_attn output (also bf16 scores scratch)
  float* na = g + (size_t)NB * S_LEN * S_LEN;              // neibor_attn output

  // scratch inside the na output region (all dead before softmax overwrites it):
  u16* Xb = (u16*)na;                                              // [8192][1024] bf16 (16 MiB)
  unsigned char* X8 = (unsigned char*)(Xb + (size_t)(NB * S_LEN) * D_MODEL);   // fp8, 8 MiB
  unsigned char* Y8 = X8 + (size_t)(NB * S_LEN) * D_MODEL;                     // fp8, 8 MiB
  u16* PT = (u16*)(Y8 + (size_t)(NB * S_LEN) * D_MODEL);           // [1024][1024] bf16 (2 MiB)
  u16* Wt = PT + (size_t)D_MODEL * D_MODEL;                        // [2048][1024] bf16 (4 MiB)
  // bf16 scores live in the g output region (overwritten by gattn at the end):
  u16* Sb = (u16*)g;                                               // [8192][2048] bf16 (32 MiB)
  // small scratch in ws:
  float* w2   = (float*)d_ws;                                      // [1024]
  float* bvec = w2 + D_MODEL;                                      // [8192]
  float* ell  = bvec + NB * S_LEN;                                 // [8192]
  float* dvec = ell + NB * S_LEN;                                  // [8192]
  float* Cpre = dvec + NB * S_LEN;                                 // [8192]

  w2_kernel<<<D_MODEL / 4, 256, 0, stream>>>(Wk, bq, w2);
  ln_kernel<<<NB * S_LEN, 256, 0, stream>>>(ctx, gamma, beta, w2, Xb, X8, bvec);
  prep_w<<<dim3(32, 64), dim3(32, 8), 0, stream>>>(Wq, Wk, Wt);

  // PT[n][k] = P[k][n], P = Wq·Wk^T  ->  PT = gemm(A=Wk^T, Bt=Wq^T)
  gemm_bt<<<dim3(8, 8, 1), 256, 0, stream>>>(Wt + (size_t)D_MODEL * D_MODEL, D_MODEL,
                                             Wt, D_MODEL,
                                             PT, D_MODEL, 1.0f, D_MODEL);
  // y = x·P  (bf16 in, fp8 out)
  gemm8p128<<<dim3(4, 64, 1), 512, 0, stream>>>(Xb, D_MODEL,
                                                PT, D_MODEL,
                                                Y8, D_MODEL, 1.0f, D_MODEL);
  // scores[b] = (y8[b] · x8[b]^T) / d  (fp8 MFMA, bf16 out)
  gemm8pF8<<<dim3(8, 8, NB), 512, 0, stream>>>(Y8, (long long)S_LEN * D_MODEL,
                                               X8, (long long)S_LEN * D_MODEL,
                                               Sb, S_LEN, (long long)S_LEN * S_LEN,
                                               1.0f / (float)D_MODEL, D_MODEL);

  softmax_kernel<<<NB * S_LEN, 256, 0, stream>>>(Sb, bvec, prior, na, ell, dvec);
  scan_kernel<<<NB, 256, 0, stream>>>(ell, Cpre);
  gattn_kernel<<<dim3(2, S_LEN, NB), 256, 0, stream>>>(Cpre, dvec, g);
}

// Round 9
// 115.934 us; speedup vs baseline: 1.2094x; 1.0680x over previous
//
#include <hip/hip_runtime.h>
#include <hip/hip_fp8.h>

#define S_LEN 2048
#define D_MODEL 1024
#define NB 4

typedef unsigned short u16;
typedef __attribute__((ext_vector_type(8))) short short8;
typedef __attribute__((ext_vector_type(4))) float f32x4;
typedef __attribute__((ext_vector_type(16))) float f32x16;
typedef __attribute__((ext_vector_type(4))) unsigned short u16x4;
typedef __attribute__((ext_vector_type(4))) int i32x4;
typedef __attribute__((ext_vector_type(8))) int i32x8;

__device__ inline u16 f2bf(float f) {
  union { float f; unsigned u; } v; v.f = f;
  unsigned u = v.u;
  unsigned r = (u + 0x7FFFu + ((u >> 16) & 1u)) >> 16;
  return (u16)r;
}

__device__ inline float bf2f(u16 b) {
  union { unsigned u; float f; } v; v.u = ((unsigned)b) << 16;
  return v.f;
}

__device__ inline unsigned char f2e4m3(float f) {
  __hip_fp8_e4m3 q(f);
  return (unsigned char)q.__x;
}

__device__ inline void glds16(const void* g, void* l) {
  __builtin_amdgcn_global_load_lds((const __attribute__((address_space(1))) void*)g,
                                   (__attribute__((address_space(3))) void*)l,
                                   16, 0, 0);
}

__device__ inline i32x8 cat8(i32x4 a, i32x4 b) {
  i32x8 r;
  r[0] = a[0]; r[1] = a[1]; r[2] = a[2]; r[3] = a[3];
  r[4] = b[0]; r[5] = b[1]; r[6] = b[2]; r[7] = b[3];
  return r;
}

// ---------------- w2[t] = sum_n Wk[t][n] * bq[n]  (one wave per row) ----------------
__global__ __launch_bounds__(256) void w2_kernel(const float* __restrict__ Wk,
                                                 const float* __restrict__ bq,
                                                 float* __restrict__ w2) {
  const int r = blockIdx.x * 4 + (threadIdx.x >> 6);
  const int lane = threadIdx.x & 63;
  const f32x4* row = (const f32x4*)(Wk + (size_t)r * D_MODEL);
  float s = 0.0f;
  #pragma unroll
  for (int c = 0; c < 4; ++c) {
    const f32x4 v = row[lane * 4 + c];
    const f32x4 b = ((const f32x4*)bq)[lane * 4 + c];
    s += v[0]*b[0] + v[1]*b[1] + v[2]*b[2] + v[3]*b[3];
  }
  for (int o = 32; o > 0; o >>= 1) s += __shfl_xor(s, o);
  if (lane == 0) w2[r] = s;
}

// ---------------- LayerNorm: fp32 in -> fp8 X8 + fused bvec ----------------
__global__ __launch_bounds__(256) void ln_kernel(const float* __restrict__ ctx,
                                                 const float* __restrict__ gamma,
                                                 const float* __restrict__ beta,
                                                 const float* __restrict__ w2,
                                                 unsigned char* __restrict__ x8,
                                                 float* __restrict__ bvec) {
  const int row = blockIdx.x;
  const int t = threadIdx.x;
  const f32x4 v = ((const f32x4*)(ctx + (size_t)row * D_MODEL))[t];
  float s = v[0] + v[1] + v[2] + v[3];
  float q = v[0]*v[0] + v[1]*v[1] + v[2]*v[2] + v[3]*v[3];
  for (int o = 32; o > 0; o >>= 1) { s += __shfl_xor(s, o); q += __shfl_xor(q, o); }
  __shared__ float rs[4], rq[4], rd[4];
  const int wave = t >> 6, lane = t & 63;
  if (lane == 0) { rs[wave] = s; rq[wave] = q; }
  __syncthreads();
  s = rs[0] + rs[1] + rs[2] + rs[3];
  q = rq[0] + rq[1] + rq[2] + rq[3];
  const float mu = s * (1.0f / D_MODEL);
  const float var = q * (1.0f / D_MODEL) - mu * mu;
  const float rstd = rsqrtf(var + 1e-3f);
  const f32x4 g4 = ((const f32x4*)gamma)[t];
  const f32x4 b4 = ((const f32x4*)beta)[t];
  const f32x4 w4 = ((const f32x4*)w2)[t];
  float xv[4];
  float dot = 0.0f;
  #pragma unroll
  for (int u = 0; u < 4; ++u) {
    xv[u] = (v[u] - mu) * rstd * g4[u] + b4[u];
    dot += xv[u] * w4[u];
  }
  unsigned pk = (unsigned)f2e4m3(xv[0]) | ((unsigned)f2e4m3(xv[1]) << 8) |
                ((unsigned)f2e4m3(xv[2]) << 16) | ((unsigned)f2e4m3(xv[3]) << 24);
  ((unsigned*)(x8 + (size_t)row * D_MODEL))[t] = pk;
  for (int of = 32; of > 0; of >>= 1) dot += __shfl_xor(dot, of);
  if (lane == 0) rd[wave] = dot;
  __syncthreads();
  if (t == 0) bvec[row] = (rd[0] + rd[1] + rd[2] + rd[3]) * (1.0f / D_MODEL);
}

// ---------------- weight prep: Wt[n][k] = bf16(W[k][n]); rows [0,1024)=Wq^T, [1024,2048)=Wk^T ----------------
__global__ __launch_bounds__(256) void prep_w(const float* __restrict__ Wq,
                                              const float* __restrict__ Wk,
                                              u16* __restrict__ Wt) {
  __shared__ float tile[32][33];
  const int k0 = blockIdx.x * 32;
  const int n0 = blockIdx.y * 32;
  const int tx = threadIdx.x, ty = threadIdx.y;
  const float* W = (n0 < D_MODEL) ? Wq : Wk;
  const int nl0 = (n0 < D_MODEL) ? n0 : (n0 - D_MODEL);
  #pragma unroll
  for (int j = 0; j < 32; j += 8)
    tile[ty + j][tx] = W[(size_t)(k0 + ty + j) * D_MODEL + nl0 + tx];
  __syncthreads();
  #pragma unroll
  for (int j = 0; j < 32; j += 8)
    Wt[(size_t)(n0 + ty + j) * D_MODEL + k0 + tx] = f2bf(tile[tx][ty + j]);
}

// ---------------- bf16 GEMM: m97-style 128x128 tile (PT only), fp8 x16 output ----------------
__global__ __launch_bounds__(256, 2) void gemm_bt(
    const u16* __restrict__ A, int lda,
    const u16* __restrict__ Bt, int ldb,
    unsigned char* __restrict__ C8, int ldc,
    float scale, int K) {
  __shared__ u16 As[128][32];
  __shared__ u16 Bs[128][32];
  const int tid = threadIdx.x;
  const int wave = tid >> 6, lane = tid & 63;
  const size_t m0 = (size_t)blockIdx.y * 128;
  const size_t n0 = (size_t)blockIdx.x * 128;
  const int wr = (wave >> 1) * 64;
  const int wc = (wave & 1) * 64;
  const int strow = wave * 16 + (lane >> 2);
  const int stslot = (lane & 3) * 8;
  const int fr = lane & 15, fq = lane >> 4;

  f32x4 acc[4][4];
  #pragma unroll
  for (int i = 0; i < 4; ++i)
    #pragma unroll
    for (int j = 0; j < 4; ++j) acc[i][j] = (f32x4)(0.0f);

  for (int k0 = 0; k0 < K; k0 += 32) {
    const u16* ga = A + (m0 + strow) * lda + k0 + stslot;
    const u16* gb = Bt + (n0 + strow) * ldb + k0 + stslot;
    glds16(ga, &As[wave * 16][0]);
    glds16(ga + (size_t)64 * lda, &As[64 + wave * 16][0]);
    glds16(gb, &Bs[wave * 16][0]);
    glds16(gb + (size_t)64 * ldb, &Bs[64 + wave * 16][0]);
    __syncthreads();
    short8 af[4], bfv[4];
    #pragma unroll
    for (int mi = 0; mi < 4; ++mi) af[mi] = *(const short8*)&As[wr + mi * 16 + fr][fq * 8];
    #pragma unroll
    for (int ni = 0; ni < 4; ++ni) bfv[ni] = *(const short8*)&Bs[wc + ni * 16 + fr][fq * 8];
    #pragma unroll
    for (int mi = 0; mi < 4; ++mi)
      #pragma unroll
      for (int ni = 0; ni < 4; ++ni)
        acc[mi][ni] = __builtin_amdgcn_mfma_f32_16x16x32_bf16(af[mi], bfv[ni], acc[mi][ni], 0, 0, 0);
    __syncthreads();
  }

  #pragma unroll
  for (int mi = 0; mi < 4; ++mi)
    #pragma unroll
    for (int ni = 0; ni < 4; ++ni) {
      const size_t row = m0 + wr + mi * 16 + fq * 4;
      const size_t col = n0 + wc + ni * 16 + fr;
      #pragma unroll
      for (int r = 0; r < 4; ++r)
        C8[(row + r) * ldc + col] = f2e4m3(acc[mi][ni][r] * scale);
    }
}

// ---------------- 128x256 fp8 GEMM (y): mfma_scale 32x32x64, BK=128, 8 waves, 2 phases/K-tile ----------------
// LDS: 2 buf x (A 128x128B + B 256x128B) = 96 KiB. Same staging swizzle / fragment reads as gemm8pF8.
__global__ __launch_bounds__(512, 2) void gemm8pF8y(
    const unsigned char* __restrict__ A8,
    const unsigned char* __restrict__ B8,
    unsigned char* __restrict__ C8, int ldc,
    float scale, int K) {
  __shared__ char smem[98304];
  const int tid = threadIdx.x;
  const int wave = tid >> 6, lane = tid & 63;
  const int wm = wave >> 2, wn = wave & 3;   // wm in [0,2), wn in [0,4)
  const size_t m0 = (size_t)blockIdx.y * 128;
  const size_t n0 = (size_t)blockIdx.x * 256;
  const unsigned char* Ab = A8 + m0 * K;
  const unsigned char* Bb = B8 + n0 * K;
  const int perL = (lane >> 3) * K + (((lane & 7) ^ (lane >> 3)) * 16);
  const int r7l = lane & 7;
  const int hi = lane >> 5;
  const int l31 = lane & 31;
  const int swk0_0 = ((hi * 2) ^ r7l) * 16;
  const int swk0_1 = ((hi * 2 + 1) ^ r7l) * 16;
  const int swk1_0 = ((4 + hi * 2) ^ r7l) * 16;
  const int swk1_1 = ((4 + hi * 2 + 1) ^ r7l) * 16;
  const int aOff = wm * 8192 + l31 * 128;           // + mt*4096 + sw
  const int bOff = 16384 + wn * 8192 + l31 * 128;   // + nt*4096 + sw

  f32x16 acc[2][2];
  #pragma unroll
  for (int i = 0; i < 2; ++i)
    #pragma unroll
    for (int j = 0; j < 2; ++j) acc[i][j] = (f32x16)(0.0f);

#define YSTG_A(BUF, KK) do { \
    glds16(Ab + (size_t)(wave * 16) * K + perL + (KK), smem + (BUF) + wave * 2048); \
    glds16(Ab + (size_t)(wave * 16 + 8) * K + perL + (KK), smem + (BUF) + wave * 2048 + 1024); } while (0)
#define YSTG_BEV(BUF, KK) do { \
    glds16(Bb + (size_t)(wave * 32) * K + perL + (KK), smem + (BUF) + 16384 + wave * 4096); \
    glds16(Bb + (size_t)(wave * 32 + 8) * K + perL + (KK), smem + (BUF) + 16384 + wave * 4096 + 1024); } while (0)
#define YSTG_BOD(BUF, KK) do { \
    glds16(Bb + (size_t)(wave * 32 + 16) * K + perL + (KK), smem + (BUF) + 16384 + wave * 4096 + 2048); \
    glds16(Bb + (size_t)(wave * 32 + 24) * K + perL + (KK), smem + (BUF) + 16384 + wave * 4096 + 3072); } while (0)

  const int NT = K >> 7;  // BK=128
  YSTG_A(0, 0); YSTG_BEV(0, 0); YSTG_BOD(0, 0);

  for (int t = 0; t < NT; ++t) {
    const int bo = (t & 1) * 49152;
    const int bn = bo ^ 49152;
    const int kk = (t + 1 < NT) ? (t + 1) * 128 : 0;
    i32x8 afr[2], bfr[2];

    // ---- phase 0: ks0 ----
    asm volatile("s_waitcnt vmcnt(0)" ::: "memory");
    asm volatile("s_barrier" ::: "memory");
    #pragma unroll
    for (int mt = 0; mt < 2; ++mt)
      afr[mt] = cat8(*(const i32x4*)(smem + bo + aOff + mt * 4096 + swk0_0),
                     *(const i32x4*)(smem + bo + aOff + mt * 4096 + swk0_1));
    #pragma unroll
    for (int nt = 0; nt < 2; ++nt)
      bfr[nt] = cat8(*(const i32x4*)(smem + bo + bOff + nt * 4096 + swk0_0),
                     *(const i32x4*)(smem + bo + bOff + nt * 4096 + swk0_1));
    YSTG_A(bn, kk);
    YSTG_BEV(bn, kk);
    __builtin_amdgcn_s_setprio(1);
    #pragma unroll
    for (int mt = 0; mt < 2; ++mt)
      #pragma unroll
      for (int nt = 0; nt < 2; ++nt)
        acc[mt][nt] = __builtin_amdgcn_mfma_scale_f32_32x32x64_f8f6f4(
            afr[mt], bfr[nt], acc[mt][nt], 0, 0, 0, 0x7F7F7F7F, 0, 0x7F7F7F7F);
    __builtin_amdgcn_s_setprio(0);

    // ---- phase 1: ks1 ----
    asm volatile("s_barrier" ::: "memory");
    #pragma unroll
    for (int mt = 0; mt < 2; ++mt)
      afr[mt] = cat8(*(const i32x4*)(smem + bo + aOff + mt * 4096 + swk1_0),
                     *(const i32x4*)(smem + bo + aOff + mt * 4096 + swk1_1));
    #pragma unroll
    for (int nt = 0; nt < 2; ++nt)
      bfr[nt] = cat8(*(const i32x4*)(smem + bo + bOff + nt * 4096 + swk1_0),
                     *(const i32x4*)(smem + bo + bOff + nt * 4096 + swk1_1));
    YSTG_BOD(bn, kk);
    __builtin_amdgcn_s_setprio(1);
    #pragma unroll
    for (int mt = 0; mt < 2; ++mt)
      #pragma unroll
      for (int nt = 0; nt < 2; ++nt)
        acc[mt][nt] = __builtin_amdgcn_mfma_scale_f32_32x32x64_f8f6f4(
            afr[mt], bfr[nt], acc[mt][nt], 0, 0, 0, 0x7F7F7F7F, 0, 0x7F7F7F7F);
    __builtin_amdgcn_s_setprio(0);
  }
#undef YSTG_A
#undef YSTG_BEV
#undef YSTG_BOD

  // C/D layout 32x32: col = lane&31, row = (r&3) + 8*(r>>2) + 4*(lane>>5)
  #pragma unroll
  for (int mt = 0; mt < 2; ++mt)
    #pragma unroll
    for (int nt = 0; nt < 2; ++nt) {
      const size_t colg = n0 + wn * 64 + nt * 32 + l31;
      #pragma unroll
      for (int r = 0; r < 16; ++r) {
        const size_t rowg = m0 + wm * 64 + mt * 32 + (r & 3) + 8 * (r >> 2) + 4 * hi;
        C8[rowg * ldc + colg] = f2e4m3(acc[mt][nt][r] * scale);
      }
    }
}

// ---------------- 256x256 fp8 GEMM (scores): mfma_scale 32x32x64, BK=128, 8 waves ----------------
__global__ __launch_bounds__(512, 2) void gemm8pF8(
    const unsigned char* __restrict__ A8, long long sA,
    const unsigned char* __restrict__ B8, long long sB,
    u16* __restrict__ C, int ldc, long long sC,
    float scale, int K) {
  __shared__ char smem[131072];
  const int tid = threadIdx.x;
  const int wave = tid >> 6, lane = tid & 63;
  const int wm = wave >> 2, wn = wave & 3;
  const int z = blockIdx.z;
  const size_t m0 = (size_t)blockIdx.y * 256;
  const size_t n0 = (size_t)blockIdx.x * 256;
  const unsigned char* Ab = A8 + (size_t)z * sA + m0 * K;
  const unsigned char* Bb = B8 + (size_t)z * sB + n0 * K;
  const int perL = (lane >> 3) * K + (((lane & 7) ^ (lane >> 3)) * 16);
  const int w4 = wave * 4;
  const int r7l = lane & 7;
  const int hi = lane >> 5;
  const int l31 = lane & 31;
  const int swk0_0 = ((hi * 2) ^ r7l) * 16;
  const int swk0_1 = ((hi * 2 + 1) ^ r7l) * 16;
  const int swk1_0 = ((4 + hi * 2) ^ r7l) * 16;
  const int swk1_1 = ((4 + hi * 2 + 1) ^ r7l) * 16;
  const int aOff = wm * 16384 + l31 * 128;
  const int bOff = 32768 + wn * 8192 + l31 * 128;

  f32x16 acc[4][2];
  #pragma unroll
  for (int i = 0; i < 4; ++i)
    #pragma unroll
    for (int j = 0; j < 2; ++j) acc[i][j] = (f32x16)(0.0f);

#define STG_A8(BUF, KK, C0) do { \
    glds16(Ab + (size_t)((w4 + (C0)) * 8) * K + perL + (KK), smem + (BUF) + (w4 + (C0)) * 1024); \
    glds16(Ab + (size_t)((w4 + (C0) + 1) * 8) * K + perL + (KK), smem + (BUF) + (w4 + (C0) + 1) * 1024); } while (0)
#define STG_B8(BUF, KK, C0) do { \
    glds16(Bb + (size_t)((w4 + (C0)) * 8) * K + perL + (KK), smem + (BUF) + 32768 + (w4 + (C0)) * 1024); \
    glds16(Bb + (size_t)((w4 + (C0) + 1) * 8) * K + perL + (KK), smem + (BUF) + 32768 + (w4 + (C0) + 1) * 1024); } while (0)

  const int NT = K >> 7;
  STG_A8(0, 0, 0); STG_A8(0, 0, 2); STG_B8(0, 0, 0); STG_B8(0, 0, 2);

  for (int t = 0; t < NT; ++t) {
    const int bo = (t & 1) * 65536;
    const int bn = bo ^ 65536;
    const int kk = (t + 1 < NT) ? (t + 1) * 128 : 0;
    i32x8 afr[4], bfr[2];

    // ---- phase 0: ks0, nt0 ----
    asm volatile("s_waitcnt vmcnt(0)" ::: "memory");
    asm volatile("s_barrier" ::: "memory");
    #pragma unroll
    for (int mt = 0; mt < 4; ++mt)
      afr[mt] = cat8(*(const i32x4*)(smem + bo + aOff + mt * 4096 + swk0_0),
                     *(const i32x4*)(smem + bo + aOff + mt * 4096 + swk0_1));
    bfr[0] = cat8(*(const i32x4*)(smem + bo + bOff + swk0_0),
                  *(const i32x4*)(smem + bo + bOff + swk0_1));
    STG_A8(bn, kk, 0); STG_B8(bn, kk, 0);
    __builtin_amdgcn_s_setprio(1);
    #pragma unroll
    for (int mt = 0; mt < 4; ++mt)
      acc[mt][0] = __builtin_amdgcn_mfma_scale_f32_32x32x64_f8f6f4(
          afr[mt], bfr[0], acc[mt][0], 0, 0, 0, 0x7F7F7F7F, 0, 0x7F7F7F7F);
    __builtin_amdgcn_s_setprio(0);

    // ---- phase 1: ks0, nt1 ----
    asm volatile("s_barrier" ::: "memory");
    bfr[1] = cat8(*(const i32x4*)(smem + bo + bOff + 4096 + swk0_0),
                  *(const i32x4*)(smem + bo + bOff + 4096 + swk0_1));
    STG_A8(bn, kk, 2); STG_B8(bn, kk, 2);
    __builtin_amdgcn_s_setprio(1);
    #pragma unroll
    for (int mt = 0; mt < 4; ++mt)
      acc[mt][1] = __builtin_amdgcn_mfma_scale_f32_32x32x64_f8f6f4(
          afr[mt], bfr[1], acc[mt][1], 0, 0, 0, 0x7F7F7F7F, 0, 0x7F7F7F7F);
    __builtin_amdgcn_s_setprio(0);

    // ---- phase 2: ks1, nt0 ----
    asm volatile("s_barrier" ::: "memory");
    #pragma unroll
    for (int mt = 0; mt < 4; ++mt)
      afr[mt] = cat8(*(const i32x4*)(smem + bo + aOff + mt * 4096 + swk1_0),
                     *(const i32x4*)(smem + bo + aOff + mt * 4096 + swk1_1));
    bfr[0] = cat8(*(const i32x4*)(smem + bo + bOff + swk1_0),
                  *(const i32x4*)(smem + bo + bOff + swk1_1));
    __builtin_amdgcn_s_setprio(1);
    #pragma unroll
    for (int mt = 0; mt < 4; ++mt)
      acc[mt][0] = __builtin_amdgcn_mfma_scale_f32_32x32x64_f8f6f4(
          afr[mt], bfr[0], acc[mt][0], 0, 0, 0, 0x7F7F7F7F, 0, 0x7F7F7F7F);
    __builtin_amdgcn_s_setprio(0);

    // ---- phase 3: ks1, nt1 ----
    asm volatile("s_barrier" ::: "memory");
    bfr[1] = cat8(*(const i32x4*)(smem + bo + bOff + 4096 + swk1_0),
                  *(const i32x4*)(smem + bo + bOff + 4096 + swk1_1));
    __builtin_amdgcn_s_setprio(1);
    #pragma unroll
    for (int mt = 0; mt < 4; ++mt)
      acc[mt][1] = __builtin_amdgcn_mfma_scale_f32_32x32x64_f8f6f4(
          afr[mt], bfr[1], acc[mt][1], 0, 0, 0, 0x7F7F7F7F, 0, 0x7F7F7F7F);
    __builtin_amdgcn_s_setprio(0);
  }
#undef STG_A8
#undef STG_B8

  u16* Cz = C + (size_t)z * sC;
  #pragma unroll
  for (int mt = 0; mt < 4; ++mt)
    #pragma unroll
    for (int nt = 0; nt < 2; ++nt) {
      const size_t colg = n0 + wn * 64 + nt * 32 + l31;
      #pragma unroll
      for (int r = 0; r < 16; ++r) {
        const size_t rowg = m0 + wm * 128 + mt * 32 + (r & 3) + 8 * (r >> 2) + 4 * hi;
        Cz[rowg * ldc + colg] = f2bf(acc[mt][nt][r] * scale);
      }
    }
}

// ---------------- row softmax + prior transform; emits na row, ell, dvec ----------------
__global__ __launch_bounds__(256) void softmax_kernel(const u16* __restrict__ Sb,
                                                      const float* __restrict__ bvec,
                                                      const float* __restrict__ prior,
                                                      float* __restrict__ na,
                                                      float* __restrict__ ell,
                                                      float* __restrict__ dvec) {
  const int row = blockIdx.x;
  const int t = threadIdx.x;
  const int b = row >> 11, i = row & (S_LEN - 1);
  const short8 sv = ((const short8*)(Sb + (size_t)row * S_LEN))[t];
  const f32x4 bv0 = ((const f32x4*)(bvec + (size_t)b * S_LEN))[t * 2];
  const f32x4 bv1 = ((const f32x4*)(bvec + (size_t)b * S_LEN))[t * 2 + 1];
  float v[8];
  #pragma unroll
  for (int u = 0; u < 8; ++u)
    v[u] = bf2f((u16)sv[u]) + ((u < 4) ? bv0[u] : bv1[u - 4]);
  float mx = v[0];
  #pragma unroll
  for (int u = 1; u < 8; ++u) mx = fmaxf(mx, v[u]);
  for (int o = 32; o > 0; o >>= 1) mx = fmaxf(mx, __shfl_xor(mx, o));
  __shared__ float red[4], red2[4];
  const int wave = t >> 6, lane = t & 63;
  if (lane == 0) red[wave] = mx;
  __syncthreads();
  mx = fmaxf(fmaxf(red[0], red[1]), fmaxf(red[2], red[3]));
  float e[8], s = 0.0f;
  #pragma unroll
  for (int u = 0; u < 8; ++u) { e[u] = __expf(v[u] - mx); s += e[u]; }
  for (int o = 32; o > 0; o >>= 1) s += __shfl_xor(s, o);
  if (lane == 0) red2[wave] = s;
  __syncthreads();
  s = red2[0] + red2[1] + red2[2] + red2[3];
  const float pr = prior[0];
  const float w = 1.0f - pr;
  const float inv = 1.0f / s;
  f32x4 o0, o1;
  #pragma unroll
  for (int u = 0; u < 4; ++u) o0[u] = pr + w * (e[u] * inv + 1e-9f);
  #pragma unroll
  for (int u = 0; u < 4; ++u) o1[u] = pr + w * (e[4 + u] * inv + 1e-9f);
  f32x4* nrow = (f32x4*)(na + (size_t)row * S_LEN);
  nrow[t * 2] = o0;
  nrow[t * 2 + 1] = o1;
  #pragma unroll
  for (int u = 0; u < 8; ++u) {
    const int j = t * 8 + u;
    const float ov = (u < 4) ? o0[u] : o1[u - 4];
    if (j == i) dvec[row] = ov;
    if (j == i + 1) ell[row] = logf(ov + 1e-9f);
  }
  if (i == S_LEN - 1 && t == 0) ell[row] = 0.0f;
}

// ---------------- exclusive prefix sum of ell -> Cpre ----------------
__global__ __launch_bounds__(256) void scan_kernel(const float* __restrict__ ell,
                                                   float* __restrict__ Cpre) {
  const int b = blockIdx.x, t = threadIdx.x;
  const float* eb = ell + (size_t)b * S_LEN;
  const f32x4 e0 = ((const f32x4*)eb)[t * 2];
  const f32x4 e1 = ((const f32x4*)eb)[t * 2 + 1];
  float ev[8];
  #pragma unroll
  for (int u = 0; u < 4; ++u) ev[u] = e0[u];
  #pragma unroll
  for (int u = 0; u < 4; ++u) ev[4 + u] = e1[u];
  float loc[8], tot = 0.0f;
  #pragma unroll
  for (int u = 0; u < 8; ++u) { loc[u] = tot; tot += ev[u]; }
  __shared__ float sbuf[256];
  sbuf[t] = tot;
  __syncthreads();
  for (int off = 1; off < 256; off <<= 1) {
    const float v = (t >= off) ? sbuf[t - off] : 0.0f;
    __syncthreads();
    sbuf[t] += v;
    __syncthreads();
  }
  const float base = (t == 0) ? 0.0f : sbuf[t - 1];
  #pragma unroll
  for (int u = 0; u < 8; ++u)
    Cpre[(size_t)b * S_LEN + t * 8 + u] = base + loc[u];
}

// ---------------- g_attn: exp(C[max]-C[min]) + 1e-9, diag from dvec ----------------
__global__ __launch_bounds__(256) void gattn_kernel(const float* __restrict__ Cpre,
                                                    const float* __restrict__ dvec,
                                                    float* __restrict__ g) {
  const int b = blockIdx.z, i = blockIdx.y;
  const int j0 = blockIdx.x * 1024 + threadIdx.x * 4;
  const float Ci = Cpre[b * S_LEN + i];
  const float di = dvec[b * S_LEN + i];
  const f32x4 Cj = *(const f32x4*)&Cpre[b * S_LEN + j0];
  f32x4 o;
  #pragma unroll
  for (int u = 0; u < 4; ++u) {
    const int j = j0 + u;
    const float arg = (j > i) ? (Cj[u] - Ci) : (Ci - Cj[u]);
    o[u] = (j == i) ? (di + 1e-9f) : (__expf(arg) + 1e-9f);
  }
  *(f32x4*)(g + ((size_t)b * S_LEN + i) * S_LEN + j0) = o;
}

extern "C" void kernel_launch(void* const* d_in, const int* in_sizes, int n_in,
                              void* d_out, int out_size, void* d_ws, size_t ws_size,
                              hipStream_t stream) {
  const float* ctx   = (const float*)d_in[0];
  // d_in[1] = eos_mask: numerically a no-op (mask * 1e-19 in fp32), never read.
  const float* prior = (const float*)d_in[2];
  const float* gamma = (const float*)d_in[3];
  const float* beta  = (const float*)d_in[4];
  const float* Wk    = (const float*)d_in[5];
  const float* Wq    = (const float*)d_in[7];
  const float* bq    = (const float*)d_in[8];

  float* g  = (float*)d_out;                               // g_attn output (also bf16 scores scratch)
  float* na = g + (size_t)NB * S_LEN * S_LEN;              // neibor_attn output

  // scratch inside the na output region (all dead before softmax overwrites it):
  unsigned char* X8 = (unsigned char*)na;                          // fp8 [8192][1024], 8 MiB
  unsigned char* Y8 = X8 + (size_t)(NB * S_LEN) * D_MODEL;         // fp8 [8192][1024], 8 MiB
  unsigned char* PT8 = Y8 + (size_t)(NB * S_LEN) * D_MODEL;        // fp8 [1024][1024], 1 MiB
  u16* Wt = (u16*)(PT8 + (size_t)D_MODEL * D_MODEL);               // [2048][1024] bf16, 4 MiB
  // bf16 scores live in the g output region (overwritten by gattn at the end):
  u16* Sb = (u16*)g;                                               // [8192][2048] bf16, 32 MiB
  // small scratch in ws:
  float* w2   = (float*)d_ws;                                      // [1024]
  float* bvec = w2 + D_MODEL;                                      // [8192]
  float* ell  = bvec + NB * S_LEN;                                 // [8192]
  float* dvec = ell + NB * S_LEN;                                  // [8192]
  float* Cpre = dvec + NB * S_LEN;                                 // [8192]

  w2_kernel<<<D_MODEL / 4, 256, 0, stream>>>(Wk, bq, w2);
  ln_kernel<<<NB * S_LEN, 256, 0, stream>>>(ctx, gamma, beta, w2, X8, bvec);
  prep_w<<<dim3(32, 64), dim3(32, 8), 0, stream>>>(Wq, Wk, Wt);

  // PT8[n][k] = fp8(16 * P[k][n]), P = Wq·Wk^T  ->  gemm(A=Wk^T, Bt=Wq^T), x16 fp8 epilogue
  gemm_bt<<<dim3(8, 8, 1), 256, 0, stream>>>(Wt + (size_t)D_MODEL * D_MODEL, D_MODEL,
                                             Wt, D_MODEL,
                                             PT8, D_MODEL, 16.0f, D_MODEL);
  // Y8 = fp8(x·P)  (fp8 MFMA; undo the x16 with scale 1/16)
  gemm8pF8y<<<dim3(4, 64, 1), 512, 0, stream>>>(X8, PT8,
                                                Y8, D_MODEL, 1.0f / 16.0f, D_MODEL);
  // scores[b] = (y8[b] · x8[b]^T) / d  (fp8 MFMA, bf16 out)
  gemm8pF8<<<dim3(8, 8, NB), 512, 0, stream>>>(Y8, (long long)S_LEN * D_MODEL,
                                               X8, (long long)S_LEN * D_MODEL,
                                               Sb, S_LEN, (long long)S_LEN * S_LEN,
                                               1.0f / (float)D_MODEL, D_MODEL);

  softmax_kernel<<<NB * S_LEN, 256, 0, stream>>>(Sb, bvec, prior, na, ell, dvec);
  scan_kernel<<<NB, 256, 0, stream>>>(ell, Cpre);
  gattn_kernel<<<dim3(2, S_LEN, NB), 256, 0, stream>>>(Cpre, dvec, g);
}